// Round 7
// baseline (671.618 us; speedup 1.0000x reference)
//
#include <hip/hip_runtime.h>
#include <hip/hip_bf16.h>
#include <stdint.h>

typedef __attribute__((ext_vector_type(8))) short short8;
typedef __attribute__((ext_vector_type(4))) short short4v;
typedef __attribute__((ext_vector_type(2))) float f32x2;
typedef __attribute__((ext_vector_type(4))) float f32x4;
typedef __attribute__((ext_vector_type(16))) float f32x16;
typedef unsigned short u16;
typedef unsigned int u32;

#define DEV __device__ __forceinline__

constexpr int Bb = 2, Ss = 4096, Cc = 640, Hh = 8, Dd = 80;
constexpr int BS = Bb * Ss;          // 8192
constexpr int NQKV = 3 * Cc;         // 1920

DEV float bf2f(u16 u) { unsigned v = ((unsigned)u) << 16; float f; __builtin_memcpy(&f, &v, 4); return f; }
DEV u16 f2bf(float f) {
    unsigned u; __builtin_memcpy(&u, &f, 4);
    u += 0x7fffu + ((u >> 16) & 1u);
    return (u16)(u >> 16);
}
DEV u32 packbf2(float a, float b) {
    float2 f2; f2.x = a; f2.y = b;
    __hip_bfloat162 h2 = __float22bfloat162_rn(f2);
    u32 r; __builtin_memcpy(&r, &h2, 4);
    return r;
}

// permlane32_swap: a' = lane<32 ? a : b[l-32];  b' = lane<32 ? a[l+32] : b
DEV void pswapf(float &a, float &b) {
#if __has_builtin(__builtin_amdgcn_permlane32_swap)
    auto r = __builtin_amdgcn_permlane32_swap(__float_as_int(a), __float_as_int(b), false, false);
    a = __int_as_float(r[0]); b = __int_as_float(r[1]);
#else
    float sa = __shfl_xor(a, 32, 64), sb = __shfl_xor(b, 32, 64);
    bool hi = (threadIdx.x & 32) != 0;
    float na = hi ? sb : a, nb = hi ? b : sa;
    a = na; b = nb;
#endif
}
DEV void pswap2(u32 &a, u32 &b) {
#if __has_builtin(__builtin_amdgcn_permlane32_swap)
    auto r = __builtin_amdgcn_permlane32_swap((int)a, (int)b, false, false);
    a = (u32)r[0]; b = (u32)r[1];
#else
    u32 sa = (u32)__shfl_xor((int)a, 32, 64), sb = (u32)__shfl_xor((int)b, 32, 64);
    bool hi = (threadIdx.x & 32) != 0;
    u32 na = hi ? sb : a, nb = hi ? b : sa;
    a = na; b = nb;
#endif
}

#define GLD16(gp, lp) __builtin_amdgcn_global_load_lds( \
    (const __attribute__((address_space(1))) void*)(gp), \
    (__attribute__((address_space(3))) void*)(lp), 16, 0, 0)

// ---------------------------------------------------------------------------
// Kernel A: hs -> bf16 (vectorized), concat bias.
// ---------------------------------------------------------------------------
__global__ void convert_kernel(const float* __restrict__ hs,
                               const float* __restrict__ bq, const float* __restrict__ bk,
                               const float* __restrict__ bv,
                               u16* __restrict__ Xb, float* __restrict__ bcat)
{
    const float QS = 0.11180339887498949f * 1.4426950408889634f;
    int tid = blockIdx.x * blockDim.x + threadIdx.x;
    int nthr = gridDim.x * blockDim.x;
    for (int i = tid; i < BS * Cc / 4; i += nthr) {
        float4 v = ((const float4*)hs)[i];
        short4v o;
        o[0] = (short)f2bf(v.x); o[1] = (short)f2bf(v.y);
        o[2] = (short)f2bf(v.z); o[3] = (short)f2bf(v.w);
        ((short4v*)Xb)[i] = o;
    }
    for (int i = tid; i < NQKV; i += nthr) {
        float v = (i < Cc) ? bq[i] * QS : (i < 2 * Cc) ? bk[i - Cc] : bv[i - 2 * Cc];
        bcat[i] = v;
    }
}

// ---------------------------------------------------------------------------
// Kernel A2: weight transpose via LDS tiles, coalesced both sides.
// ---------------------------------------------------------------------------
__global__ __launch_bounds__(256) void wtrans_kernel(
    const float* __restrict__ Wq, const float* __restrict__ Wk,
    const float* __restrict__ Wv, const float* __restrict__ Wo,
    u16* __restrict__ WTqkv, u16* __restrict__ WTo)
{
    __shared__ float T[32][33];
    const float QS = 0.11180339887498949f * 1.4426950408889634f;
    int tile = blockIdx.x;            // 4 * 20 * 20
    int wsel = tile / 400;
    int tt = tile - wsel * 400;
    int tr = tt / 20, tc = tt - (tt / 20) * 20;
    const float* W = (wsel == 0) ? Wq : (wsel == 1) ? Wk : (wsel == 2) ? Wv : Wo;
    float sc = (wsel == 0) ? QS : 1.0f;
    int r = threadIdx.x >> 3, c4 = (threadIdx.x & 7) * 4;
    float4 v = *(const float4*)(W + (size_t)(tr * 32 + r) * Cc + tc * 32 + c4);
    T[r][c4 + 0] = v.x; T[r][c4 + 1] = v.y; T[r][c4 + 2] = v.z; T[r][c4 + 3] = v.w;
    __syncthreads();
    short4v o;
#pragma unroll
    for (int j = 0; j < 4; j++) o[j] = (short)f2bf(T[c4 + j][r] * sc);
    u16* dst = (wsel < 3) ? (WTqkv + (size_t)(wsel * Cc + tc * 32 + r) * Cc + tr * 32 + c4)
                          : (WTo + (size_t)(tc * 32 + r) * Cc + tr * 32 + c4);
    *(short4v*)dst = o;
}

// ---------------------------------------------------------------------------
// Kernel B: bf16 GEMM  Out[m][n] = sum_k A[m][k] * Bt[n][k] + bias[n]
// ---------------------------------------------------------------------------
template <int N_TOTAL>
__global__ __launch_bounds__(256) void gemm_bf16(
    const u16* __restrict__ A, const u16* __restrict__ Bt,
    const float* __restrict__ bias, u16* __restrict__ Out, int K)
{
    constexpr int BKP = 40;
    __shared__ __align__(16) u16 As[128 * BKP];
    __shared__ __align__(16) u16 Bs[128 * BKP];

    const int mBase = blockIdx.x * 128;
    const int nBase = blockIdx.y * 128;
    const int t = threadIdx.x, lane = t & 63, w = t >> 6;
    const int wr = w >> 1, wc = w & 1;
    const int l15 = lane & 15, g = lane >> 4;

    f32x4 acc[4][4] = {};
    const int rowA = t >> 1;
    const int colA = (t & 1) * 16;

    for (int k0 = 0; k0 < K; k0 += 32) {
        const u16* pa = A + (size_t)(mBase + rowA) * K + k0 + colA;
        const u16* pb = Bt + (size_t)(nBase + rowA) * K + k0 + colA;
        short8 a0 = *(const short8*)pa;
        short8 a1 = *(const short8*)(pa + 8);
        short8 b0 = *(const short8*)pb;
        short8 b1 = *(const short8*)(pb + 8);
        *(short8*)&As[rowA * BKP + colA] = a0;
        *(short8*)&As[rowA * BKP + colA + 8] = a1;
        *(short8*)&Bs[rowA * BKP + colA] = b0;
        *(short8*)&Bs[rowA * BKP + colA + 8] = b1;
        __syncthreads();
        short8 af[4], bf[4];
#pragma unroll
        for (int i = 0; i < 4; i++) {
            af[i] = *(const short8*)&As[(wr * 64 + i * 16 + l15) * BKP + g * 8];
            bf[i] = *(const short8*)&Bs[(wc * 64 + i * 16 + l15) * BKP + g * 8];
        }
#pragma unroll
        for (int mi = 0; mi < 4; mi++)
#pragma unroll
            for (int ni = 0; ni < 4; ni++)
                acc[mi][ni] = __builtin_amdgcn_mfma_f32_16x16x32_bf16(af[mi], bf[ni], acc[mi][ni], 0, 0, 0);
        __syncthreads();
    }

#pragma unroll
    for (int mi = 0; mi < 4; mi++)
#pragma unroll
        for (int ni = 0; ni < 4; ni++) {
            int col = nBase + wc * 64 + ni * 16 + l15;
            float bb = bias[col];
#pragma unroll
            for (int r = 0; r < 4; r++) {
                int row = mBase + wr * 64 + mi * 16 + g * 4 + r;
                Out[(size_t)row * N_TOTAL + col] = f2bf(acc[mi][ni][r] + bb);
            }
        }
}

// ---------------------------------------------------------------------------
// Kernel B2: transpose V part of QKV -> VTg[b*8+h][d][s]
// ---------------------------------------------------------------------------
__global__ __launch_bounds__(256) void vtrans_kernel(const u16* __restrict__ QKV,
                                                     u16* __restrict__ VTg)
{
    __shared__ __align__(16) u16 T[80][72];
    const int st = blockIdx.x, bh = blockIdx.y;
    const int b = bh >> 3, h = bh & 7;
    const int t = threadIdx.x;
    const u16* src = QKV + ((size_t)(b * Ss + st * 64)) * NQKV + 2 * Cc + h * Dd;
    for (int i = t; i < 640; i += 256) {
        int r = i / 10, c = i % 10;
        short8 v = *(const short8*)(src + (size_t)r * NQKV + c * 8);
#pragma unroll
        for (int j = 0; j < 8; j++) T[c * 8 + j][r] = (u16)v[j];
    }
    __syncthreads();
    u16* dst = VTg + ((size_t)bh * Dd) * Ss + st * 64;
    for (int i = t; i < 640; i += 256) {
        int d = i / 8, c = i % 8;
        short8 v = *(const short8*)&T[d][c * 8];
        *(short8*)(dst + (size_t)d * Ss + c * 8) = v;
    }
}

// ---------------------------------------------------------------------------
// Kernel C: flash attention, 32x32x16 MFMA, swapped operands (S^T, O^T).
// Grid (32 qt, 16 bh, 2 kv-splits); 4 waves x 32 q. SINGLE-buffered K and V
// (LDS 22528 incl. Ob overlay -> 7-block LDS cap, grid-limited 4/CU).
// Two-barrier pipeline: QK^T | bar | stageK(kt+1) softmax PV | bar | stageV(kt+1).
// ---------------------------------------------------------------------------
constexpr int OBP = 88;

__global__ __launch_bounds__(256, 6) void attn_kernel(
    const u16* __restrict__ QKV, const u16* __restrict__ VTg,
    u16* __restrict__ N0, u16* __restrict__ N1,
    float* __restrict__ Mp, float* __restrict__ Lp)
{
    // [0,10240): K [10 chunks][64 kv][16B]
    // [10240,20480): V [80 d][8 chunks][16B] (chunk XOR-swizzled)
    // [0,22528): Ob overlay (post-loop)
    __shared__ __align__(16) char smem[22528];

    const int qt = blockIdx.x;
    const int bh = blockIdx.y;
    const int kvs = blockIdx.z;
    const int b = bh >> 3, h = bh & 7;
    const int t = threadIdx.x, lane = t & 63, w = t >> 6;
    const int l31 = lane & 31, e = lane >> 5;

    const size_t rowBase = (size_t)b * Ss;
    const int q0 = qt * 128;
    const int kvBase = kvs * (Ss / 2);
    constexpr int NT = (Ss / 2) / 64;   // 32

    const int lq8 = lane >> 3;
    const int vcg = (lane & 7) ^ lq8;   // XOR-swizzled global chunk for V stage
    const u16* kg0 = QKV + (rowBase + kvBase + lane) * NQKV + Cc + h * Dd;
    const u16* vg0 = VTg + ((size_t)bh * Dd) * Ss + kvBase + vcg * 8;

    // Q fragments (B-operand: col = q = l31, k-elems at e*8)
    short8 qB[5];
    {
        const u16* qp = QKV + (rowBase + q0 + w * 32 + l31) * NQKV + h * Dd + e * 8;
#pragma unroll
        for (int ks = 0; ks < 5; ks++) qB[ks] = *(const short8*)(qp + ks * 16);
    }

    auto stageK = [&](int kt) {
#pragma unroll
        for (int j = 0; j < 3; j++) {
            int gi = w + 4 * j;
            if (gi < 10)
                GLD16(kg0 + (size_t)kt * 64 * NQKV + gi * 8, smem + gi * 1024);
        }
    };
    auto stageV = [&](int kt) {
#pragma unroll
        for (int j = 0; j < 3; j++) {
            int gi = w + 4 * j;
            if (gi < 10)
                GLD16(vg0 + (size_t)(gi * 8 + lq8) * Ss + kt * 64,
                      smem + 10240 + gi * 1024);
        }
    };

    stageK(0);
    stageV(0);
    __syncthreads();   // tile 0 in LDS

    float mrow = -1e30f, lrow = 0.f;
    f32x16 oacc[3] = {};
    const int csl_base = l31 & 7;
    const int vr2 = 64 + (l31 & 15);   // n2==2 clamp (d>=80 rows discarded)

    for (int kt = 0; kt < NT; ++kt) {
        const bool more = (kt + 1 < NT);

        // S^T[kv][q] = K Q^T   (reads K buf)
        f32x16 s2[2];
        __builtin_amdgcn_s_setprio(1);
#pragma unroll
        for (int n = 0; n < 2; n++) {
            f32x16 a = {};
#pragma unroll
            for (int ks = 0; ks < 5; ks++) {
                short8 kf = *(const short8*)(smem + ((2 * ks + e) * 64 + n * 32 + l31) * 16);
                a = __builtin_amdgcn_mfma_f32_32x32x16_bf16(kf, qB[ks], a, 0, 0, 0);
            }
            s2[n] = a;
        }
        __builtin_amdgcn_s_setprio(0);

        __syncthreads();            // K reads done block-wide
        if (more) stageK(kt + 1);   // overwrite K buf; covered by softmax+PV

        // max over 32 scores (max3-friendly triples)
#define SV(j) ((j) < 16 ? s2[0][(j)] : s2[1][(j) - 16])
        float tt[11];
#pragma unroll
        for (int i = 0; i < 10; i++)
            tt[i] = fmaxf(fmaxf(SV(3 * i), SV(3 * i + 1)), SV(3 * i + 2));
        tt[10] = fmaxf(SV(30), SV(31));
#undef SV
        float u0 = fmaxf(fmaxf(tt[0], tt[1]), tt[2]);
        float u1 = fmaxf(fmaxf(tt[3], tt[4]), tt[5]);
        float u2 = fmaxf(fmaxf(tt[6], tt[7]), tt[8]);
        float u3 = fmaxf(tt[9], tt[10]);
        float vm = fmaxf(fmaxf(u0, u1), fmaxf(u2, u3));
        { float va = vm, vb = vm; pswapf(va, vb); vm = fmaxf(va, vb); }

        // defer-max (T13): rescale only when max grows by > 8 (log2 domain)
        if (__any(vm > mrow + 8.0f)) {
            float mnew = fmaxf(mrow, vm);
            float al = __builtin_amdgcn_exp2f(mrow - mnew);
            mrow = mnew;
            lrow *= al;
#pragma unroll
            for (int n = 0; n < 3; n++)
#pragma unroll
                for (int r = 0; r < 16; r++) oacc[n][r] *= al;
        }

        u32 pd[2][8];
        f32x2 tsv = {0.f, 0.f};
#pragma unroll
        for (int n = 0; n < 2; n++)
#pragma unroll
            for (int m = 0; m < 8; m++) {
                float pa = __builtin_amdgcn_exp2f(s2[n][2 * m] - mrow);
                float pb = __builtin_amdgcn_exp2f(s2[n][2 * m + 1] - mrow);
                f32x2 pp; pp[0] = pa; pp[1] = pb;
                tsv += pp;
                pd[n][m] = packbf2(pa, pb);
            }
        float ts = tsv[0] + tsv[1];
        { float ta = ts, tb = ts; pswapf(ta, tb); ts = ta + tb; }
        lrow += ts;

        // PV: O^T[d][q] += V^T[d][kv] * P^T[kv][q]   (reads V buf)
        __builtin_amdgcn_s_setprio(1);
#pragma unroll
        for (int ks = 0; ks < 4; ks++) {
            const int n = ks >> 1, bb2 = ks & 1;
            u32 x0 = pd[n][4 * bb2 + 0], x1 = pd[n][4 * bb2 + 1];
            u32 x2 = pd[n][4 * bb2 + 2], x3 = pd[n][4 * bb2 + 3];
            pswap2(x0, x2); pswap2(x1, x3);
            union { u32 u[4]; short8 v; } pB;
            pB.u[0] = x0; pB.u[1] = x1; pB.u[2] = x2; pB.u[3] = x3;
            const int csl = (2 * ks + e) ^ csl_base;
#pragma unroll
            for (int n2 = 0; n2 < 3; n2++) {
                const int arow = (n2 == 2) ? vr2 : (n2 * 32 + l31);
                short8 vf = *(const short8*)(smem + 10240 + (arow * 8 + csl) * 16);
                oacc[n2] = __builtin_amdgcn_mfma_f32_32x32x16_bf16(vf, pB.v, oacc[n2], 0, 0, 0);
            }
        }
        __builtin_amdgcn_s_setprio(0);

        __syncthreads();            // V reads done; K(kt+1) drained per-wave
        if (more) stageV(kt + 1);   // overwrite V buf; covered by next QK^T
    }

    if (e == 0) {
        int mi = kvs * 65536 + bh * Ss + q0 + w * 32 + l31;
        Mp[mi] = mrow;
        Lp[mi] = lrow;
    }

    // pack numerator O^T -> Ob overlay, then coalesced dump
    u16* Ob = (u16*)smem;
#pragma unroll
    for (int n = 0; n < 3; n++)
#pragma unroll
        for (int r = 0; r < 16; r += 2) {
            if (n == 2 && r >= 8) continue;   // d >= 80
            int dloc = n * 32 + (r & 3) + 8 * (r >> 2) + 4 * e;
            u32 pk = packbf2(oacc[n][r], oacc[n][r + 1]);
            *(u32*)&Ob[(w * 32 + l31) * OBP + dloc] = pk;
        }
    __syncthreads();

    u16* Np = kvs ? N1 : N0;
    const int NS = kvs ? NQKV : Cc;
    const int cb = h * Dd;
#pragma unroll
    for (int i = 0; i < 5; i++) {
        int gidx = i * 256 + t;
        int row = gidx / 10, gi = gidx % 10;
        short8 v = *(const short8*)&Ob[row * OBP + gi * 8];
        *(short8*)(Np + (rowBase + q0 + row) * NS + cb + gi * 8) = v;
    }
}

// ---------------------------------------------------------------------------
// Kernel D: O-projection with FUSED kv-split merge + bias + residual, fp32 out.
// A[row][k] = N0[row][k]*w0(row,h) + N1[row][k]*w1(row,h),  h = k/80.
// ---------------------------------------------------------------------------
__global__ __launch_bounds__(256) void gemm_oproj(
    const u16* __restrict__ N0, const u16* __restrict__ N1,
    const u16* __restrict__ Bt,
    const float* __restrict__ Mp, const float* __restrict__ Lp,
    const float* __restrict__ bias, const float* __restrict__ resid,
    float* __restrict__ Out)
{
    constexpr int BKP = 40;
    __shared__ __align__(16) u16 As[128 * BKP];
    __shared__ __align__(16) u16 Bs[128 * BKP];
    __shared__ float WF[128][8][2];   // merged softmax weights w0,w1 (incl. 1/l)

    const int mBase = blockIdx.x * 128;
    const int nBase = blockIdx.y * 128;
    const int t = threadIdx.x, lane = t & 63, w = t >> 6;
    const int wr = w >> 1, wc = w & 1;
    const int l15 = lane & 15, g = lane >> 4;

    // prologue: per-row per-head merge weights
    for (int i = t; i < 1024; i += 256) {
        int r = i >> 3, h = i & 7;
        int row = mBase + r;
        int bb = row >> 12, q = row & 4095;
        int mi = (bb * 8 + h) * Ss + q;
        float m0 = Mp[mi], m1 = Mp[65536 + mi];
        float l0 = Lp[mi], l1 = Lp[65536 + mi];
        float m = fmaxf(m0, m1);
        float w0 = exp2f(m0 - m), w1 = exp2f(m1 - m);
        float rl = 1.0f / (l0 * w0 + l1 * w1);
        WF[r][h][0] = w0 * rl;
        WF[r][h][1] = w1 * rl;
    }
    __syncthreads();

    f32x4 acc[4][4] = {};
    const int rowA = t >> 1;
    const int colA = (t & 1) * 16;

    for (int k0 = 0; k0 < Cc; k0 += 32) {
        const int kc = k0 + colA;          // 16-col segment, within one head
        const int hh = kc / 80;
        float w0 = WF[rowA][hh][0], w1 = WF[rowA][hh][1];
        const u16* p0 = N0 + (size_t)(mBase + rowA) * Cc + kc;
        const u16* p1 = N1 + (size_t)(mBase + rowA) * NQKV + kc;
        short8 a0 = *(const short8*)p0;
        short8 a1 = *(const short8*)(p0 + 8);
        short8 c0 = *(const short8*)p1;
        short8 c1 = *(const short8*)(p1 + 8);
        u32 mg[8];
#pragma unroll
        for (int j = 0; j < 4; j++) {
            mg[j] = packbf2(bf2f((u16)a0[2 * j]) * w0 + bf2f((u16)c0[2 * j]) * w1,
                            bf2f((u16)a0[2 * j + 1]) * w0 + bf2f((u16)c0[2 * j + 1]) * w1);
            mg[4 + j] = packbf2(bf2f((u16)a1[2 * j]) * w0 + bf2f((u16)c1[2 * j]) * w1,
                                bf2f((u16)a1[2 * j + 1]) * w0 + bf2f((u16)c1[2 * j + 1]) * w1);
        }
        const u16* pb = Bt + (size_t)(nBase + rowA) * Cc + kc;
        short8 b0 = *(const short8*)pb;
        short8 b1 = *(const short8*)(pb + 8);
#pragma unroll
        for (int j = 0; j < 4; j++) {
            *(u32*)&As[rowA * BKP + colA + 2 * j] = mg[j];
            *(u32*)&As[rowA * BKP + colA + 8 + 2 * j] = mg[4 + j];
        }
        *(short8*)&Bs[rowA * BKP + colA] = b0;
        *(short8*)&Bs[rowA * BKP + colA + 8] = b1;
        __syncthreads();
        short8 af[4], bf[4];
#pragma unroll
        for (int i = 0; i < 4; i++) {
            af[i] = *(const short8*)&As[(wr * 64 + i * 16 + l15) * BKP + g * 8];
            bf[i] = *(const short8*)&Bs[(wc * 64 + i * 16 + l15) * BKP + g * 8];
        }
#pragma unroll
        for (int mi = 0; mi < 4; mi++)
#pragma unroll
            for (int ni = 0; ni < 4; ni++)
                acc[mi][ni] = __builtin_amdgcn_mfma_f32_16x16x32_bf16(af[mi], bf[ni], acc[mi][ni], 0, 0, 0);
        __syncthreads();
    }

#pragma unroll
    for (int mi = 0; mi < 4; mi++)
#pragma unroll
        for (int ni = 0; ni < 4; ni++) {
            int col = nBase + wc * 64 + ni * 16 + l15;
            float bb = bias[col];
#pragma unroll
            for (int r = 0; r < 4; r++) {
                int row = mBase + wr * 64 + mi * 16 + g * 4 + r;
                Out[(size_t)row * Cc + col] = acc[mi][ni][r] + bb + resid[(size_t)row * Cc + col];
            }
        }
}

// ---------------------------------------------------------------------------
extern "C" void kernel_launch(void* const* d_in, const int* in_sizes, int n_in,
                              void* d_out, int out_size, void* d_ws, size_t ws_size,
                              hipStream_t stream) {
    (void)in_sizes; (void)n_in; (void)out_size; (void)ws_size;
    const float* hs = (const float*)d_in[0];
    const float* Wq = (const float*)d_in[1];
    const float* bq = (const float*)d_in[2];
    const float* Wk = (const float*)d_in[3];
    const float* bk = (const float*)d_in[4];
    const float* Wv = (const float*)d_in[5];
    const float* bv = (const float*)d_in[6];
    const float* Wo = (const float*)d_in[7];
    const float* bo = (const float*)d_in[8];
    float* out = (float*)d_out;

    char* ws = (char*)d_ws;
    u16*   Xb    = (u16*)  (ws + 0);          // 8192*640*2   = 10,485,760 (reused as VTg)
    u16*   WTqkv = (u16*)  (ws + 10485760);   // 1920*640*2   =  2,457,600
    u16*   WTo   = (u16*)  (ws + 12943360);   // 640*640*2    =    819,200
    float* bcat  = (float*)(ws + 13762560);   // 1920*4       =      7,680
    u16*   QKV   = (u16*)  (ws + 13770240);   // 8192*1920*2  = 31,457,280
    u16*   AOb   = (u16*)  (ws + 45227520);   // 8192*640*2   = 10,485,760 (N0)
    float* Mp    = (float*)(ws + 55713280);   // 2*16*4096*4  =    524,288
    float* Lp    = (float*)(ws + 56237568);   // 2*16*4096*4  =    524,288
    u16*   VTg   = Xb;                        // overlay: Xb dead after gemm_bf16
    u16*   N1    = QKV + 2 * Cc;              // overlay: V-cols of QKV dead after vtrans

    convert_kernel<<<dim3(2048), dim3(256), 0, stream>>>(hs, bq, bk, bv, Xb, bcat);
    wtrans_kernel<<<dim3(1600), dim3(256), 0, stream>>>(Wq, Wk, Wv, Wo, WTqkv, WTo);
    gemm_bf16<NQKV><<<dim3(64, 15), dim3(256), 0, stream>>>(Xb, WTqkv, bcat, QKV, Cc);
    vtrans_kernel<<<dim3(64, 16), dim3(256), 0, stream>>>(QKV, VTg);
    attn_kernel<<<dim3(32, 16, 2), dim3(256), 0, stream>>>(QKV, VTg, AOb, N1, Mp, Lp);
    gemm_oproj<<<dim3(64, 5), dim3(256), 0, stream>>>(AOb, N1, WTo, Mp, Lp, bo, hs, out);
}

// Round 8
// 217.360 us; speedup vs baseline: 3.0899x; 3.0899x over previous
//
#include <hip/hip_runtime.h>
#include <hip/hip_bf16.h>
#include <stdint.h>

typedef __attribute__((ext_vector_type(8))) short short8;
typedef __attribute__((ext_vector_type(4))) short short4v;
typedef __attribute__((ext_vector_type(2))) float f32x2;
typedef __attribute__((ext_vector_type(4))) float f32x4;
typedef __attribute__((ext_vector_type(16))) float f32x16;
typedef unsigned short u16;
typedef unsigned int u32;

#define DEV __device__ __forceinline__

constexpr int Bb = 2, Ss = 4096, Cc = 640, Hh = 8, Dd = 80;
constexpr int BS = Bb * Ss;          // 8192
constexpr int NQKV = 3 * Cc;         // 1920

DEV float bf2f(u16 u) { unsigned v = ((unsigned)u) << 16; float f; __builtin_memcpy(&f, &v, 4); return f; }
DEV u16 f2bf(float f) {
    unsigned u; __builtin_memcpy(&u, &f, 4);
    u += 0x7fffu + ((u >> 16) & 1u);
    return (u16)(u >> 16);
}
DEV u32 packbf2(float a, float b) {
    float2 f2; f2.x = a; f2.y = b;
    __hip_bfloat162 h2 = __float22bfloat162_rn(f2);
    u32 r; __builtin_memcpy(&r, &h2, 4);
    return r;
}

// permlane32_swap: a' = lane<32 ? a : b[l-32];  b' = lane<32 ? a[l+32] : b
DEV void pswapf(float &a, float &b) {
#if __has_builtin(__builtin_amdgcn_permlane32_swap)
    auto r = __builtin_amdgcn_permlane32_swap(__float_as_int(a), __float_as_int(b), false, false);
    a = __int_as_float(r[0]); b = __int_as_float(r[1]);
#else
    float sa = __shfl_xor(a, 32, 64), sb = __shfl_xor(b, 32, 64);
    bool hi = (threadIdx.x & 32) != 0;
    float na = hi ? sb : a, nb = hi ? b : sa;
    a = na; b = nb;
#endif
}
DEV void pswap2(u32 &a, u32 &b) {
#if __has_builtin(__builtin_amdgcn_permlane32_swap)
    auto r = __builtin_amdgcn_permlane32_swap((int)a, (int)b, false, false);
    a = (u32)r[0]; b = (u32)r[1];
#else
    u32 sa = (u32)__shfl_xor((int)a, 32, 64), sb = (u32)__shfl_xor((int)b, 32, 64);
    bool hi = (threadIdx.x & 32) != 0;
    u32 na = hi ? sb : a, nb = hi ? b : sa;
    a = na; b = nb;
#endif
}

#define GLD16(gp, lp) __builtin_amdgcn_global_load_lds( \
    (const __attribute__((address_space(1))) void*)(gp), \
    (__attribute__((address_space(3))) void*)(lp), 16, 0, 0)

// ---------------------------------------------------------------------------
// Kernel A: hs -> bf16 (vectorized), concat bias.
// ---------------------------------------------------------------------------
__global__ void convert_kernel(const float* __restrict__ hs,
                               const float* __restrict__ bq, const float* __restrict__ bk,
                               const float* __restrict__ bv,
                               u16* __restrict__ Xb, float* __restrict__ bcat)
{
    const float QS = 0.11180339887498949f * 1.4426950408889634f;
    int tid = blockIdx.x * blockDim.x + threadIdx.x;
    int nthr = gridDim.x * blockDim.x;
    for (int i = tid; i < BS * Cc / 4; i += nthr) {
        float4 v = ((const float4*)hs)[i];
        short4v o;
        o[0] = (short)f2bf(v.x); o[1] = (short)f2bf(v.y);
        o[2] = (short)f2bf(v.z); o[3] = (short)f2bf(v.w);
        ((short4v*)Xb)[i] = o;
    }
    for (int i = tid; i < NQKV; i += nthr) {
        float v = (i < Cc) ? bq[i] * QS : (i < 2 * Cc) ? bk[i - Cc] : bv[i - 2 * Cc];
        bcat[i] = v;
    }
}

// ---------------------------------------------------------------------------
// Kernel A2: weight transpose via LDS tiles, coalesced both sides.
// ---------------------------------------------------------------------------
__global__ __launch_bounds__(256) void wtrans_kernel(
    const float* __restrict__ Wq, const float* __restrict__ Wk,
    const float* __restrict__ Wv, const float* __restrict__ Wo,
    u16* __restrict__ WTqkv, u16* __restrict__ WTo)
{
    __shared__ float T[32][33];
    const float QS = 0.11180339887498949f * 1.4426950408889634f;
    int tile = blockIdx.x;            // 4 * 20 * 20
    int wsel = tile / 400;
    int tt = tile - wsel * 400;
    int tr = tt / 20, tc = tt - (tt / 20) * 20;
    const float* W = (wsel == 0) ? Wq : (wsel == 1) ? Wk : (wsel == 2) ? Wv : Wo;
    float sc = (wsel == 0) ? QS : 1.0f;
    int r = threadIdx.x >> 3, c4 = (threadIdx.x & 7) * 4;
    float4 v = *(const float4*)(W + (size_t)(tr * 32 + r) * Cc + tc * 32 + c4);
    T[r][c4 + 0] = v.x; T[r][c4 + 1] = v.y; T[r][c4 + 2] = v.z; T[r][c4 + 3] = v.w;
    __syncthreads();
    short4v o;
#pragma unroll
    for (int j = 0; j < 4; j++) o[j] = (short)f2bf(T[c4 + j][r] * sc);
    u16* dst = (wsel < 3) ? (WTqkv + (size_t)(wsel * Cc + tc * 32 + r) * Cc + tr * 32 + c4)
                          : (WTo + (size_t)(tc * 32 + r) * Cc + tr * 32 + c4);
    *(short4v*)dst = o;
}

// ---------------------------------------------------------------------------
// Kernel B: bf16 GEMM  Out[m][n] = sum_k A[m][k] * Bt[n][k] + bias[n]
// ---------------------------------------------------------------------------
template <int N_TOTAL>
__global__ __launch_bounds__(256) void gemm_bf16(
    const u16* __restrict__ A, const u16* __restrict__ Bt,
    const float* __restrict__ bias, u16* __restrict__ Out, int K)
{
    constexpr int BKP = 40;
    __shared__ __align__(16) u16 As[128 * BKP];
    __shared__ __align__(16) u16 Bs[128 * BKP];

    const int mBase = blockIdx.x * 128;
    const int nBase = blockIdx.y * 128;
    const int t = threadIdx.x, lane = t & 63, w = t >> 6;
    const int wr = w >> 1, wc = w & 1;
    const int l15 = lane & 15, g = lane >> 4;

    f32x4 acc[4][4] = {};
    const int rowA = t >> 1;
    const int colA = (t & 1) * 16;

    for (int k0 = 0; k0 < K; k0 += 32) {
        const u16* pa = A + (size_t)(mBase + rowA) * K + k0 + colA;
        const u16* pb = Bt + (size_t)(nBase + rowA) * K + k0 + colA;
        short8 a0 = *(const short8*)pa;
        short8 a1 = *(const short8*)(pa + 8);
        short8 b0 = *(const short8*)pb;
        short8 b1 = *(const short8*)(pb + 8);
        *(short8*)&As[rowA * BKP + colA] = a0;
        *(short8*)&As[rowA * BKP + colA + 8] = a1;
        *(short8*)&Bs[rowA * BKP + colA] = b0;
        *(short8*)&Bs[rowA * BKP + colA + 8] = b1;
        __syncthreads();
        short8 af[4], bf[4];
#pragma unroll
        for (int i = 0; i < 4; i++) {
            af[i] = *(const short8*)&As[(wr * 64 + i * 16 + l15) * BKP + g * 8];
            bf[i] = *(const short8*)&Bs[(wc * 64 + i * 16 + l15) * BKP + g * 8];
        }
#pragma unroll
        for (int mi = 0; mi < 4; mi++)
#pragma unroll
            for (int ni = 0; ni < 4; ni++)
                acc[mi][ni] = __builtin_amdgcn_mfma_f32_16x16x32_bf16(af[mi], bf[ni], acc[mi][ni], 0, 0, 0);
        __syncthreads();
    }

#pragma unroll
    for (int mi = 0; mi < 4; mi++)
#pragma unroll
        for (int ni = 0; ni < 4; ni++) {
            int col = nBase + wc * 64 + ni * 16 + l15;
            float bb = bias[col];
#pragma unroll
            for (int r = 0; r < 4; r++) {
                int row = mBase + wr * 64 + mi * 16 + g * 4 + r;
                Out[(size_t)row * N_TOTAL + col] = f2bf(acc[mi][ni][r] + bb);
            }
        }
}

// ---------------------------------------------------------------------------
// Kernel B2: transpose V part of QKV -> VTg[b*8+h][d][s]
// ---------------------------------------------------------------------------
__global__ __launch_bounds__(256) void vtrans_kernel(const u16* __restrict__ QKV,
                                                     u16* __restrict__ VTg)
{
    __shared__ __align__(16) u16 T[80][72];
    const int st = blockIdx.x, bh = blockIdx.y;
    const int b = bh >> 3, h = bh & 7;
    const int t = threadIdx.x;
    const u16* src = QKV + ((size_t)(b * Ss + st * 64)) * NQKV + 2 * Cc + h * Dd;
    for (int i = t; i < 640; i += 256) {
        int r = i / 10, c = i % 10;
        short8 v = *(const short8*)(src + (size_t)r * NQKV + c * 8);
#pragma unroll
        for (int j = 0; j < 8; j++) T[c * 8 + j][r] = (u16)v[j];
    }
    __syncthreads();
    u16* dst = VTg + ((size_t)bh * Dd) * Ss + st * 64;
    for (int i = t; i < 640; i += 256) {
        int d = i / 8, c = i % 8;
        short8 v = *(const short8*)&T[d][c * 8];
        *(short8*)(dst + (size_t)d * Ss + c * 8) = v;
    }
}

// ---------------------------------------------------------------------------
// Kernel C: flash attention, 32x32x16 MFMA, swapped operands (S^T, O^T).
// Grid (32 qt, 16 bh, 2 kv-splits); 4 waves x 32 q. SINGLE-buffered K and V
// (LDS 22528 incl. Ob overlay). Two-barrier pipeline:
// QK^T | bar | stageK(kt+1) softmax PV | bar | stageV(kt+1).
// __launch_bounds__(256,4): R7's (256,6) forced VGPR=40 -> total spill,
// 2.7 GB/dispatch scratch traffic (FETCH 1.33 GB, WRITE 1.28 GB). Keep 4.
// ---------------------------------------------------------------------------
constexpr int OBP = 88;

__global__ __launch_bounds__(256, 4) void attn_kernel(
    const u16* __restrict__ QKV, const u16* __restrict__ VTg,
    u16* __restrict__ N0, u16* __restrict__ N1,
    float* __restrict__ Mp, float* __restrict__ Lp)
{
    // [0,10240): K [10 chunks][64 kv][16B]
    // [10240,20480): V [80 d][8 chunks][16B] (chunk XOR-swizzled)
    // [0,22528): Ob overlay (post-loop)
    __shared__ __align__(16) char smem[22528];

    const int qt = blockIdx.x;
    const int bh = blockIdx.y;
    const int kvs = blockIdx.z;
    const int b = bh >> 3, h = bh & 7;
    const int t = threadIdx.x, lane = t & 63, w = t >> 6;
    const int l31 = lane & 31, e = lane >> 5;

    const size_t rowBase = (size_t)b * Ss;
    const int q0 = qt * 128;
    const int kvBase = kvs * (Ss / 2);
    constexpr int NT = (Ss / 2) / 64;   // 32

    const int lq8 = lane >> 3;
    const int vcg = (lane & 7) ^ lq8;   // XOR-swizzled global chunk for V stage
    const u16* kg0 = QKV + (rowBase + kvBase + lane) * NQKV + Cc + h * Dd;
    const u16* vg0 = VTg + ((size_t)bh * Dd) * Ss + kvBase + vcg * 8;

    // Q fragments (B-operand: col = q = l31, k-elems at e*8)
    short8 qB[5];
    {
        const u16* qp = QKV + (rowBase + q0 + w * 32 + l31) * NQKV + h * Dd + e * 8;
#pragma unroll
        for (int ks = 0; ks < 5; ks++) qB[ks] = *(const short8*)(qp + ks * 16);
    }

    auto stageK = [&](int kt) {
#pragma unroll
        for (int j = 0; j < 3; j++) {
            int gi = w + 4 * j;
            if (gi < 10)
                GLD16(kg0 + (size_t)kt * 64 * NQKV + gi * 8, smem + gi * 1024);
        }
    };
    auto stageV = [&](int kt) {
#pragma unroll
        for (int j = 0; j < 3; j++) {
            int gi = w + 4 * j;
            if (gi < 10)
                GLD16(vg0 + (size_t)(gi * 8 + lq8) * Ss + kt * 64,
                      smem + 10240 + gi * 1024);
        }
    };

    stageK(0);
    stageV(0);
    __syncthreads();   // tile 0 in LDS

    float mrow = -1e30f, lrow = 0.f;
    f32x16 oacc[3] = {};
    const int csl_base = l31 & 7;
    const int vr2 = 64 + (l31 & 15);   // n2==2 clamp (d>=80 rows discarded)

    for (int kt = 0; kt < NT; ++kt) {
        const bool more = (kt + 1 < NT);

        // S^T[kv][q] = K Q^T   (reads K buf)
        f32x16 s2[2];
        __builtin_amdgcn_s_setprio(1);
#pragma unroll
        for (int n = 0; n < 2; n++) {
            f32x16 a = {};
#pragma unroll
            for (int ks = 0; ks < 5; ks++) {
                short8 kf = *(const short8*)(smem + ((2 * ks + e) * 64 + n * 32 + l31) * 16);
                a = __builtin_amdgcn_mfma_f32_32x32x16_bf16(kf, qB[ks], a, 0, 0, 0);
            }
            s2[n] = a;
        }
        __builtin_amdgcn_s_setprio(0);

        __syncthreads();            // K reads done block-wide
        if (more) stageK(kt + 1);   // overwrite K buf; covered by softmax+PV

        // max over 32 scores (max3-friendly triples)
#define SV(j) ((j) < 16 ? s2[0][(j)] : s2[1][(j) - 16])
        float tt[11];
#pragma unroll
        for (int i = 0; i < 10; i++)
            tt[i] = fmaxf(fmaxf(SV(3 * i), SV(3 * i + 1)), SV(3 * i + 2));
        tt[10] = fmaxf(SV(30), SV(31));
#undef SV
        float u0 = fmaxf(fmaxf(tt[0], tt[1]), tt[2]);
        float u1 = fmaxf(fmaxf(tt[3], tt[4]), tt[5]);
        float u2 = fmaxf(fmaxf(tt[6], tt[7]), tt[8]);
        float u3 = fmaxf(tt[9], tt[10]);
        float vm = fmaxf(fmaxf(u0, u1), fmaxf(u2, u3));
        { float va = vm, vb = vm; pswapf(va, vb); vm = fmaxf(va, vb); }

        // defer-max (T13): rescale only when max grows by > 8 (log2 domain)
        if (__any(vm > mrow + 8.0f)) {
            float mnew = fmaxf(mrow, vm);
            float al = __builtin_amdgcn_exp2f(mrow - mnew);
            mrow = mnew;
            lrow *= al;
#pragma unroll
            for (int n = 0; n < 3; n++)
#pragma unroll
                for (int r = 0; r < 16; r++) oacc[n][r] *= al;
        }

        u32 pd[2][8];
        f32x2 tsv = {0.f, 0.f};
#pragma unroll
        for (int n = 0; n < 2; n++)
#pragma unroll
            for (int m = 0; m < 8; m++) {
                float pa = __builtin_amdgcn_exp2f(s2[n][2 * m] - mrow);
                float pb = __builtin_amdgcn_exp2f(s2[n][2 * m + 1] - mrow);
                f32x2 pp; pp[0] = pa; pp[1] = pb;
                tsv += pp;
                pd[n][m] = packbf2(pa, pb);
            }
        float ts = tsv[0] + tsv[1];
        { float ta = ts, tb = ts; pswapf(ta, tb); ts = ta + tb; }
        lrow += ts;

        // PV: O^T[d][q] += V^T[d][kv] * P^T[kv][q]   (reads V buf)
        __builtin_amdgcn_s_setprio(1);
#pragma unroll
        for (int ks = 0; ks < 4; ks++) {
            const int n = ks >> 1, bb2 = ks & 1;
            u32 x0 = pd[n][4 * bb2 + 0], x1 = pd[n][4 * bb2 + 1];
            u32 x2 = pd[n][4 * bb2 + 2], x3 = pd[n][4 * bb2 + 3];
            pswap2(x0, x2); pswap2(x1, x3);
            union { u32 u[4]; short8 v; } pB;
            pB.u[0] = x0; pB.u[1] = x1; pB.u[2] = x2; pB.u[3] = x3;
            const int csl = (2 * ks + e) ^ csl_base;
#pragma unroll
            for (int n2 = 0; n2 < 3; n2++) {
                const int arow = (n2 == 2) ? vr2 : (n2 * 32 + l31);
                short8 vf = *(const short8*)(smem + 10240 + (arow * 8 + csl) * 16);
                oacc[n2] = __builtin_amdgcn_mfma_f32_32x32x16_bf16(vf, pB.v, oacc[n2], 0, 0, 0);
            }
        }
        __builtin_amdgcn_s_setprio(0);

        __syncthreads();            // V reads done; K(kt+1) drained per-wave
        if (more) stageV(kt + 1);   // overwrite V buf; covered by next QK^T
    }

    if (e == 0) {
        int mi = kvs * 65536 + bh * Ss + q0 + w * 32 + l31;
        Mp[mi] = mrow;
        Lp[mi] = lrow;
    }

    // pack numerator O^T -> Ob overlay, then coalesced dump
    u16* Ob = (u16*)smem;
#pragma unroll
    for (int n = 0; n < 3; n++)
#pragma unroll
        for (int r = 0; r < 16; r += 2) {
            if (n == 2 && r >= 8) continue;   // d >= 80
            int dloc = n * 32 + (r & 3) + 8 * (r >> 2) + 4 * e;
            u32 pk = packbf2(oacc[n][r], oacc[n][r + 1]);
            *(u32*)&Ob[(w * 32 + l31) * OBP + dloc] = pk;
        }
    __syncthreads();

    u16* Np = kvs ? N1 : N0;
    const int NS = kvs ? NQKV : Cc;
    const int cb = h * Dd;
#pragma unroll
    for (int i = 0; i < 5; i++) {
        int gidx = i * 256 + t;
        int row = gidx / 10, gi = gidx % 10;
        short8 v = *(const short8*)&Ob[row * OBP + gi * 8];
        *(short8*)(Np + (rowBase + q0 + row) * NS + cb + gi * 8) = v;
    }
}

// ---------------------------------------------------------------------------
// Kernel D: O-projection with FUSED kv-split merge + bias + residual, fp32 out.
// A[row][k] = N0[row][k]*w0(row,h) + N1[row][k]*w1(row,h),  h = k/80.
// ---------------------------------------------------------------------------
__global__ __launch_bounds__(256) void gemm_oproj(
    const u16* __restrict__ N0, const u16* __restrict__ N1,
    const u16* __restrict__ Bt,
    const float* __restrict__ Mp, const float* __restrict__ Lp,
    const float* __restrict__ bias, const float* __restrict__ resid,
    float* __restrict__ Out)
{
    constexpr int BKP = 40;
    __shared__ __align__(16) u16 As[128 * BKP];
    __shared__ __align__(16) u16 Bs[128 * BKP];
    __shared__ float WF[128][8][2];   // merged softmax weights w0,w1 (incl. 1/l)

    const int mBase = blockIdx.x * 128;
    const int nBase = blockIdx.y * 128;
    const int t = threadIdx.x, lane = t & 63, w = t >> 6;
    const int wr = w >> 1, wc = w & 1;
    const int l15 = lane & 15, g = lane >> 4;

    // prologue: per-row per-head merge weights
    for (int i = t; i < 1024; i += 256) {
        int r = i >> 3, h = i & 7;
        int row = mBase + r;
        int bb = row >> 12, q = row & 4095;
        int mi = (bb * 8 + h) * Ss + q;
        float m0 = Mp[mi], m1 = Mp[65536 + mi];
        float l0 = Lp[mi], l1 = Lp[65536 + mi];
        float m = fmaxf(m0, m1);
        float w0 = exp2f(m0 - m), w1 = exp2f(m1 - m);
        float rl = 1.0f / (l0 * w0 + l1 * w1);
        WF[r][h][0] = w0 * rl;
        WF[r][h][1] = w1 * rl;
    }
    __syncthreads();

    f32x4 acc[4][4] = {};
    const int rowA = t >> 1;
    const int colA = (t & 1) * 16;

    for (int k0 = 0; k0 < Cc; k0 += 32) {
        const int kc = k0 + colA;          // 16-col segment, within one head
        const int hh = kc / 80;
        float w0 = WF[rowA][hh][0], w1 = WF[rowA][hh][1];
        const u16* p0 = N0 + (size_t)(mBase + rowA) * Cc + kc;
        const u16* p1 = N1 + (size_t)(mBase + rowA) * NQKV + kc;
        short8 a0 = *(const short8*)p0;
        short8 a1 = *(const short8*)(p0 + 8);
        short8 c0 = *(const short8*)p1;
        short8 c1 = *(const short8*)(p1 + 8);
        u32 mg[8];
#pragma unroll
        for (int j = 0; j < 4; j++) {
            mg[j] = packbf2(bf2f((u16)a0[2 * j]) * w0 + bf2f((u16)c0[2 * j]) * w1,
                            bf2f((u16)a0[2 * j + 1]) * w0 + bf2f((u16)c0[2 * j + 1]) * w1);
            mg[4 + j] = packbf2(bf2f((u16)a1[2 * j]) * w0 + bf2f((u16)c1[2 * j]) * w1,
                                bf2f((u16)a1[2 * j + 1]) * w0 + bf2f((u16)c1[2 * j + 1]) * w1);
        }
        const u16* pb = Bt + (size_t)(nBase + rowA) * Cc + kc;
        short8 b0 = *(const short8*)pb;
        short8 b1 = *(const short8*)(pb + 8);
#pragma unroll
        for (int j = 0; j < 4; j++) {
            *(u32*)&As[rowA * BKP + colA + 2 * j] = mg[j];
            *(u32*)&As[rowA * BKP + colA + 8 + 2 * j] = mg[4 + j];
        }
        *(short8*)&Bs[rowA * BKP + colA] = b0;
        *(short8*)&Bs[rowA * BKP + colA + 8] = b1;
        __syncthreads();
        short8 af[4], bf[4];
#pragma unroll
        for (int i = 0; i < 4; i++) {
            af[i] = *(const short8*)&As[(wr * 64 + i * 16 + l15) * BKP + g * 8];
            bf[i] = *(const short8*)&Bs[(wc * 64 + i * 16 + l15) * BKP + g * 8];
        }
#pragma unroll
        for (int mi = 0; mi < 4; mi++)
#pragma unroll
            for (int ni = 0; ni < 4; ni++)
                acc[mi][ni] = __builtin_amdgcn_mfma_f32_16x16x32_bf16(af[mi], bf[ni], acc[mi][ni], 0, 0, 0);
        __syncthreads();
    }

#pragma unroll
    for (int mi = 0; mi < 4; mi++)
#pragma unroll
        for (int ni = 0; ni < 4; ni++) {
            int col = nBase + wc * 64 + ni * 16 + l15;
            float bb = bias[col];
#pragma unroll
            for (int r = 0; r < 4; r++) {
                int row = mBase + wr * 64 + mi * 16 + g * 4 + r;
                Out[(size_t)row * Cc + col] = acc[mi][ni][r] + bb + resid[(size_t)row * Cc + col];
            }
        }
}

// ---------------------------------------------------------------------------
extern "C" void kernel_launch(void* const* d_in, const int* in_sizes, int n_in,
                              void* d_out, int out_size, void* d_ws, size_t ws_size,
                              hipStream_t stream) {
    (void)in_sizes; (void)n_in; (void)out_size; (void)ws_size;
    const float* hs = (const float*)d_in[0];
    const float* Wq = (const float*)d_in[1];
    const float* bq = (const float*)d_in[2];
    const float* Wk = (const float*)d_in[3];
    const float* bk = (const float*)d_in[4];
    const float* Wv = (const float*)d_in[5];
    const float* bv = (const float*)d_in[6];
    const float* Wo = (const float*)d_in[7];
    const float* bo = (const float*)d_in[8];
    float* out = (float*)d_out;

    char* ws = (char*)d_ws;
    u16*   Xb    = (u16*)  (ws + 0);          // 8192*640*2   = 10,485,760 (reused as VTg)
    u16*   WTqkv = (u16*)  (ws + 10485760);   // 1920*640*2   =  2,457,600
    u16*   WTo   = (u16*)  (ws + 12943360);   // 640*640*2    =    819,200
    float* bcat  = (float*)(ws + 13762560);   // 1920*4       =      7,680
    u16*   QKV   = (u16*)  (ws + 13770240);   // 8192*1920*2  = 31,457,280
    u16*   AOb   = (u16*)  (ws + 45227520);   // 8192*640*2   = 10,485,760 (N0)
    float* Mp    = (float*)(ws + 55713280);   // 2*16*4096*4  =    524,288
    float* Lp    = (float*)(ws + 56237568);   // 2*16*4096*4  =    524,288
    u16*   VTg   = Xb;                        // overlay: Xb dead after gemm_bf16
    u16*   N1    = QKV + 2 * Cc;              // overlay: V-cols of QKV dead after vtrans

    convert_kernel<<<dim3(2048), dim3(256), 0, stream>>>(hs, bq, bk, bv, Xb, bcat);
    wtrans_kernel<<<dim3(1600), dim3(256), 0, stream>>>(Wq, Wk, Wv, Wo, WTqkv, WTo);
    gemm_bf16<NQKV><<<dim3(64, 15), dim3(256), 0, stream>>>(Xb, WTqkv, bcat, QKV, Cc);
    vtrans_kernel<<<dim3(64, 16), dim3(256), 0, stream>>>(QKV, VTg);
    attn_kernel<<<dim3(32, 16, 2), dim3(256), 0, stream>>>(QKV, VTg, AOb, N1, Mp, Lp);
    gemm_oproj<<<dim3(64, 5), dim3(256), 0, stream>>>(AOb, N1, WTo, Mp, Lp, bo, hs, out);
}